// Round 6
// baseline (62.094 us; speedup 1.0000x reference)
//
#include <hip/hip_runtime.h>
#include <hip/hip_bf16.h>

typedef __attribute__((ext_vector_type(8))) short short8;
typedef __attribute__((ext_vector_type(4))) float f32x4;
typedef __attribute__((ext_vector_type(2))) unsigned u32x2;

#define DEG 5
#define FDIM 128
#define MT 64
#define NTHR 256
#define LROW 136   // 128 + 8 shorts pad

// Exact collapse of the Shapley subset enumeration (slots symmetric, c1
// depends only on |S|):  s_i = (1 + 147/360) x_i + (-29/600) sum_j x_nbr[j]
#define CSELF 1.4083333333333334f
#define ALPHA (-0.04833333333333333f)

__device__ __forceinline__ short f2bf(float f) {
    unsigned u = __builtin_bit_cast(unsigned, f);
    unsigned r = (u + 0x7fffu + ((u >> 16) & 1u)) >> 16;
    return (short)(r & 0xffffu);
}
__device__ __forceinline__ float bf2f(short s) {
    return __builtin_bit_cast(float, (unsigned)((unsigned short)s) << 16);
}

// ---- manual OCP e4m3fn codec (FTZ denormals; |v| << 448 so no overflow path) ----
__device__ __forceinline__ unsigned f32_to_fp8(float x) {
    unsigned u = __builtin_bit_cast(unsigned, x);
    unsigned s = (u >> 24) & 0x80u;
    unsigned t = u & 0x7FFFFFFFu;
    unsigned r = t + 0x7FFFFu + ((t >> 20) & 1u);   // RNE at bit 20
    unsigned em = (r >> 20);
    em = (em < 968u) ? 0u : (em - 960u);
    return s | (em & 0x7Fu);
}
__device__ __forceinline__ float fp8_to_f32(unsigned b) {
    unsigned s = (b & 0x80u) << 24;
    unsigned em = b & 0x7Fu;
    unsigned f = s | ((em + 960u) << 20);
    return (em < 8u) ? __builtin_bit_cast(float, s) : __builtin_bit_cast(float, f);
}

// ---- prep: W (fp32 [128][128]) -> bf16 fragments in MFMA fragment-linear order ----
__global__ __launch_bounds__(256) void prep_w_kernel(
    const float* __restrict__ W, short* __restrict__ wswz)
{
    int t = blockIdx.x * 256 + threadIdx.x;   // 0..2047
    int frag = t >> 6;
    int lane = t & 63;
    int tt = frag >> 2;
    int kk = frag & 3;
    int lr = lane & 15;
    int lg = lane >> 4;
    const float4* wp = reinterpret_cast<const float4*>(W + (tt * 16 + lr) * FDIM + kk * 32 + lg * 8);
    float4 w0 = wp[0], w1 = wp[1];
    short8 v;
    v[0] = f2bf(w0.x); v[1] = f2bf(w0.y); v[2] = f2bf(w0.z); v[3] = f2bf(w0.w);
    v[4] = f2bf(w1.x); v[5] = f2bf(w1.y); v[6] = f2bf(w1.z); v[7] = f2bf(w1.w);
    *reinterpret_cast<short8*>(wswz + (size_t)t * 8) = v;
}

// ---- kernel 1: Y = x @ W^T -> bf16 Y (self path) + fp8 Y8 (gather path) ----
__global__ __launch_bounds__(NTHR) void gemm_y_kernel(
    const float* __restrict__ x,
    const short* __restrict__ wswz,
    short* __restrict__ Y,
    unsigned char* __restrict__ Y8,
    int n)
{
    __shared__ short sS[MT * LROW];
    const int tid = threadIdx.x;
    const int base = blockIdx.x * MT;

    // stage x rows -> bf16 LDS (x is read exactly once -> nontemporal)
    for (int t = tid; t < MT * 16; t += NTHR) {
        int m = t >> 4;
        int c = t & 15;
        int node = base + m;
        short8 v;
        if (node < n) {
            const f32x4* xp = reinterpret_cast<const f32x4*>(x + (size_t)node * FDIM + c * 8);
            f32x4 s0 = __builtin_nontemporal_load(xp);
            f32x4 s1 = __builtin_nontemporal_load(xp + 1);
            v[0] = f2bf(s0[0]); v[1] = f2bf(s0[1]); v[2] = f2bf(s0[2]); v[3] = f2bf(s0[3]);
            v[4] = f2bf(s1[0]); v[5] = f2bf(s1[1]); v[6] = f2bf(s1[2]); v[7] = f2bf(s1[3]);
        } else {
            v = (short8)0;
        }
        *reinterpret_cast<short8*>(&sS[m * LROW + c * 8]) = v;
    }
    __syncthreads();

    const int wave = tid >> 6;
    const int lane = tid & 63;
    const int lr = lane & 15;
    const int lg = lane >> 4;

    short8 afrag[4];
    const short* arow = &sS[(wave * 16 + lr) * LROW];
    #pragma unroll
    for (int kk = 0; kk < 4; ++kk)
        afrag[kk] = *reinterpret_cast<const short8*>(arow + kk * 32 + lg * 8);
    __syncthreads();

    f32x4 acc[8];
    #pragma unroll
    for (int t = 0; t < 8; ++t) acc[t] = (f32x4){0.f, 0.f, 0.f, 0.f};

    #pragma unroll
    for (int t = 0; t < 8; ++t) {
        #pragma unroll
        for (int kk = 0; kk < 4; ++kk) {
            short8 bfrag = *reinterpret_cast<const short8*>(
                wswz + (((size_t)(t * 4 + kk) * 64 + lane) * 8));
            acc[t] = __builtin_amdgcn_mfma_f32_16x16x32_bf16(afrag[kk], bfrag, acc[t], 0, 0, 0);
        }
    }

    #pragma unroll
    for (int t = 0; t < 8; ++t) {
        #pragma unroll
        for (int i = 0; i < 4; ++i) {
            sS[(wave * 16 + lg * 4 + i) * LROW + t * 16 + lr] = f2bf(acc[t][i]);
        }
    }
    __syncthreads();

    for (int t = tid; t < MT * 16; t += NTHR) {
        int m = t >> 4;
        int c = t & 15;
        int node = base + m;
        if (node < n) {
            short8 v = *reinterpret_cast<const short8*>(&sS[m * LROW + c * 8]);
            *reinterpret_cast<short8*>(Y + (size_t)node * FDIM + c * 8) = v;
            unsigned d0 = 0, d1 = 0;
            #pragma unroll
            for (int k = 0; k < 4; ++k)
                d0 |= f32_to_fp8(bf2f(v[k])) << (8 * k);
            #pragma unroll
            for (int k = 0; k < 4; ++k)
                d1 |= f32_to_fp8(bf2f(v[4 + k])) << (8 * k);
            u32x2 pk; pk[0] = d0; pk[1] = d1;
            *reinterpret_cast<u32x2*>(Y8 + (size_t)node * FDIM + c * 8) = pk;
        }
    }
}

// ---- kernel 2: out = relu(CSELF*Y_i + ALPHA*sum_nbr Y8_j) ----
// ALL 24 loads per thread hoisted before any use: 4 node-slots x (5 gathers +
// 1 self) in static fully-unrolled register arrays -> 4x the per-wave MLP.
// out store is nontemporal (never re-read; keep Y8 resident in L2).
__global__ __launch_bounds__(NTHR) void combine_kernel(
    const short* __restrict__ Y,
    const unsigned char* __restrict__ Y8,
    const int* __restrict__ col,
    float* __restrict__ out,
    int n)
{
    __shared__ int sIdx[MT * DEG];
    const int tid = threadIdx.x;
    const int base = blockIdx.x * MT;

    for (int i = tid; i < MT * DEG; i += NTHR) {
        int e = base * DEG + i;
        sIdx[i] = (e < n * DEG) ? col[e] : 0;
    }
    __syncthreads();

    const int slot = tid >> 4;   // node slot within 16-row group
    const int c = tid & 15;      // 8-elem chunk within row

    u32x2 g[4][DEG];             // gather payloads (fp8), 40 VGPRs
    short8 sv[4];                // self payloads (bf16), 16 VGPRs

    #pragma unroll
    for (int u = 0; u < 4; ++u) {
        int ms = u * 16 + slot;
        int node = base + ms;
        int nc = node < n ? node : 0;                 // clamp tail loads
        sv[u] = *reinterpret_cast<const short8*>(Y + (size_t)nc * FDIM + c * 8);
        #pragma unroll
        for (int j = 0; j < DEG; ++j) {
            int nb = sIdx[ms * DEG + j];
            g[u][j] = *reinterpret_cast<const u32x2*>(Y8 + (size_t)nb * FDIM + c * 8);
        }
    }

    #pragma unroll
    for (int u = 0; u < 4; ++u) {
        int node = base + u * 16 + slot;
        if (node < n) {
            float r[8];
            #pragma unroll
            for (int k = 0; k < 8; ++k) {
                unsigned sh = 8 * (k & 3);
                float s = 0.f;
                #pragma unroll
                for (int j = 0; j < DEG; ++j) {
                    unsigned w = (k < 4) ? g[u][j][0] : g[u][j][1];
                    s += fp8_to_f32((w >> sh) & 0xFFu);
                }
                float v = CSELF * bf2f(sv[u][k]) + ALPHA * s;
                r[k] = v > 0.f ? v : 0.f;
            }
            f32x4* op = reinterpret_cast<f32x4*>(out + (size_t)node * FDIM + c * 8);
            __builtin_nontemporal_store((f32x4){r[0], r[1], r[2], r[3]}, op);
            __builtin_nontemporal_store((f32x4){r[4], r[5], r[6], r[7]}, op + 1);
        }
    }
}

// ---- fallback (fused, round-2 style) if d_ws too small ----
__global__ __launch_bounds__(NTHR) void shapley_gnn_kernel(
    const float* __restrict__ x,
    const int* __restrict__ col,
    const short* __restrict__ wswz,
    float* __restrict__ out,
    int n)
{
    __shared__ short sS[MT * LROW];
    __shared__ int sIdx[MT * DEG];

    const int tid = threadIdx.x;
    const int base = blockIdx.x * MT;

    for (int i = tid; i < MT * DEG; i += NTHR) {
        int e = base * DEG + i;
        sIdx[i] = (e < n * DEG) ? col[e] : 0;
    }
    __syncthreads();

    for (int t = tid; t < MT * 16; t += NTHR) {
        int m = t >> 4;
        int c = t & 15;
        int node = base + m;
        float a0, a1, a2, a3, a4, a5, a6, a7;
        if (node < n) {
            const float4* xp = reinterpret_cast<const float4*>(x + (size_t)node * FDIM + c * 8);
            float4 s0 = xp[0], s1 = xp[1];
            a0 = CSELF * s0.x; a1 = CSELF * s0.y; a2 = CSELF * s0.z; a3 = CSELF * s0.w;
            a4 = CSELF * s1.x; a5 = CSELF * s1.y; a6 = CSELF * s1.z; a7 = CSELF * s1.w;
            #pragma unroll
            for (int j = 0; j < DEG; ++j) {
                int nb = sIdx[m * DEG + j];
                const float4* np = reinterpret_cast<const float4*>(x + (size_t)nb * FDIM + c * 8);
                float4 b0 = np[0], b1 = np[1];
                a0 += ALPHA * b0.x; a1 += ALPHA * b0.y; a2 += ALPHA * b0.z; a3 += ALPHA * b0.w;
                a4 += ALPHA * b1.x; a5 += ALPHA * b1.y; a6 += ALPHA * b1.z; a7 += ALPHA * b1.w;
            }
        } else {
            a0 = a1 = a2 = a3 = a4 = a5 = a6 = a7 = 0.f;
        }
        short8 v;
        v[0] = f2bf(a0); v[1] = f2bf(a1); v[2] = f2bf(a2); v[3] = f2bf(a3);
        v[4] = f2bf(a4); v[5] = f2bf(a5); v[6] = f2bf(a6); v[7] = f2bf(a7);
        *reinterpret_cast<short8*>(&sS[m * LROW + c * 8]) = v;
    }
    __syncthreads();

    const int wave = tid >> 6;
    const int lane = tid & 63;
    const int lr = lane & 15;
    const int lg = lane >> 4;

    short8 afrag[4];
    const short* arow = &sS[(wave * 16 + lr) * LROW];
    #pragma unroll
    for (int kk = 0; kk < 4; ++kk)
        afrag[kk] = *reinterpret_cast<const short8*>(arow + kk * 32 + lg * 8);

    f32x4 acc[8];
    #pragma unroll
    for (int t = 0; t < 8; ++t) acc[t] = (f32x4){0.f, 0.f, 0.f, 0.f};

    #pragma unroll
    for (int t = 0; t < 8; ++t) {
        #pragma unroll
        for (int kk = 0; kk < 4; ++kk) {
            short8 bfrag = *reinterpret_cast<const short8*>(
                wswz + (((size_t)(t * 4 + kk) * 64 + lane) * 8));
            acc[t] = __builtin_amdgcn_mfma_f32_16x16x32_bf16(afrag[kk], bfrag, acc[t], 0, 0, 0);
        }
    }

    #pragma unroll
    for (int t = 0; t < 8; ++t) {
        #pragma unroll
        for (int i = 0; i < 4; ++i) {
            int nrow = base + wave * 16 + lg * 4 + i;
            if (nrow < n) {
                float v = acc[t][i];
                out[(size_t)nrow * FDIM + t * 16 + lr] = v > 0.f ? v : 0.f;
            }
        }
    }
}

extern "C" void kernel_launch(void* const* d_in, const int* in_sizes, int n_in,
                              void* d_out, int out_size, void* d_ws, size_t ws_size,
                              hipStream_t stream) {
    const float* x  = (const float*)d_in[0];
    const int* ei   = (const int*)d_in[1];
    const float* W  = (const float*)d_in[2];
    float* out      = (float*)d_out;

    int n = in_sizes[0] / FDIM;                   // 100000 nodes
    const int* col = ei + (size_t)n * DEG;        // second row of edge_index

    short* wswz = (short*)d_ws;                   // 32 KB fragment buffer
    size_t y_off  = 32768;
    size_t y_sz   = (size_t)n * FDIM * sizeof(short);
    size_t y8_off = (y_off + y_sz + 255) & ~(size_t)255;
    size_t need   = y8_off + (size_t)n * FDIM;

    hipLaunchKernelGGL(prep_w_kernel, dim3(8), dim3(256), 0, stream, W, wswz);

    int blocks = (n + MT - 1) / MT;
    if (ws_size >= need) {
        short* Y          = (short*)((char*)d_ws + y_off);
        unsigned char* Y8 = (unsigned char*)d_ws + y8_off;
        hipLaunchKernelGGL(gemm_y_kernel, dim3(blocks), dim3(NTHR), 0, stream,
                           x, wswz, Y, Y8, n);
        hipLaunchKernelGGL(combine_kernel, dim3(blocks), dim3(NTHR), 0, stream,
                           Y, Y8, col, out, n);
    } else {
        hipLaunchKernelGGL(shapley_gnn_kernel, dim3(blocks), dim3(NTHR), 0, stream,
                           x, col, wswz, out, n);
    }
}

// Round 7
// 56.197 us; speedup vs baseline: 1.1050x; 1.1050x over previous
//
#include <hip/hip_runtime.h>
#include <hip/hip_bf16.h>

typedef __attribute__((ext_vector_type(8))) short short8;
typedef __attribute__((ext_vector_type(4))) float f32x4;
typedef __attribute__((ext_vector_type(2))) unsigned u32x2;

#define DEG 5
#define FDIM 128
#define MT 64
#define NTHR 256
#define LROW 136   // 128 + 8 shorts pad

// Exact collapse of the Shapley subset enumeration (slots symmetric, c1
// depends only on |S|):  s_i = (1 + 147/360) x_i + (-29/600) sum_j x_nbr[j]
#define CSELF 1.4083333333333334f
#define ALPHA (-0.04833333333333333f)

__device__ __forceinline__ short f2bf(float f) {
    unsigned u = __builtin_bit_cast(unsigned, f);
    unsigned r = (u + 0x7fffu + ((u >> 16) & 1u)) >> 16;
    return (short)(r & 0xffffu);
}
__device__ __forceinline__ float bf2f(short s) {
    return __builtin_bit_cast(float, (unsigned)((unsigned short)s) << 16);
}

// ---- manual OCP e4m3fn codec (FTZ denormals; |x| <= ~6 so no overflow path) ----
__device__ __forceinline__ unsigned f32_to_fp8(float x) {
    unsigned u = __builtin_bit_cast(unsigned, x);
    unsigned s = (u >> 24) & 0x80u;
    unsigned t = u & 0x7FFFFFFFu;
    unsigned r = t + 0x7FFFFu + ((t >> 20) & 1u);   // RNE at bit 20
    unsigned em = (r >> 20);
    em = (em < 968u) ? 0u : (em - 960u);
    return s | (em & 0x7Fu);
}
__device__ __forceinline__ float fp8_to_f32(unsigned b) {
    unsigned s = (b & 0x80u) << 24;
    unsigned em = b & 0x7Fu;
    unsigned f = s | ((em + 960u) << 20);
    return (em < 8u) ? __builtin_bit_cast(float, s) : __builtin_bit_cast(float, f);
}

// ---- prep: W (fp32 [128][128]) -> bf16 fragments in MFMA fragment-linear order ----
__global__ __launch_bounds__(256) void prep_w_kernel(
    const float* __restrict__ W, short* __restrict__ wswz)
{
    int t = blockIdx.x * 256 + threadIdx.x;   // 0..2047
    int frag = t >> 6;
    int lane = t & 63;
    int tt = frag >> 2;
    int kk = frag & 3;
    int lr = lane & 15;
    int lg = lane >> 4;
    const float4* wp = reinterpret_cast<const float4*>(W + (tt * 16 + lr) * FDIM + kk * 32 + lg * 8);
    float4 w0 = wp[0], w1 = wp[1];
    short8 v;
    v[0] = f2bf(w0.x); v[1] = f2bf(w0.y); v[2] = f2bf(w0.z); v[3] = f2bf(w0.w);
    v[4] = f2bf(w1.x); v[5] = f2bf(w1.y); v[6] = f2bf(w1.z); v[7] = f2bf(w1.w);
    *reinterpret_cast<short8*>(wswz + (size_t)t * 8) = v;
}

// ---- k1: x8 = fp8(x), pure streaming convert (8 elems/thread) ----
__global__ __launch_bounds__(256) void conv_x8_kernel(
    const float* __restrict__ x, unsigned char* __restrict__ x8, long total8)
{
    long t = (long)blockIdx.x * 256 + threadIdx.x;   // one per 8 elems
    if (t < total8) {
        const f32x4* xp = reinterpret_cast<const f32x4*>(x + t * 8);
        f32x4 a = xp[0], b = xp[1];
        unsigned d0 = f32_to_fp8(a[0]) | (f32_to_fp8(a[1]) << 8)
                    | (f32_to_fp8(a[2]) << 16) | (f32_to_fp8(a[3]) << 24);
        unsigned d1 = f32_to_fp8(b[0]) | (f32_to_fp8(b[1]) << 8)
                    | (f32_to_fp8(b[2]) << 16) | (f32_to_fp8(b[3]) << 24);
        u32x2 pk; pk[0] = d0; pk[1] = d1;
        *reinterpret_cast<u32x2*>(x8 + t * 8) = pk;
    }
}

// ---- k2 (fused): stage s_i = CSELF*x_i + ALPHA*sum_nbr x8_j -> LDS bf16,
//      then out = relu(S @ W^T) via MFMA. Gather rows are 128B = 1 line,
//      working set 12.8 MB (L3-resident). All loads hoisted per thread. ----
__global__ __launch_bounds__(NTHR) void shapley_gnn_kernel(
    const float* __restrict__ x,
    const unsigned char* __restrict__ x8,
    const int* __restrict__ col,
    const short* __restrict__ wswz,
    float* __restrict__ out,
    int n)
{
    __shared__ short sS[MT * LROW];
    __shared__ int sIdx[MT * DEG];

    const int tid = threadIdx.x;
    const int base = blockIdx.x * MT;

    for (int i = tid; i < MT * DEG; i += NTHR) {
        int e = base * DEG + i;
        sIdx[i] = (e < n * DEG) ? col[e] : 0;
    }
    __syncthreads();

    const int slot = tid >> 4;   // node slot within 16-row group (0..15)
    const int c = tid & 15;      // 8-elem chunk within row

    // hoisted loads: 4 node-slots x (self fp32 pair + 5 fp8 gathers)
    f32x4 xs[4][2];
    u32x2 g[4][DEG];
    #pragma unroll
    for (int u = 0; u < 4; ++u) {
        int ms = u * 16 + slot;
        int node = base + ms;
        int nc = node < n ? node : 0;
        const f32x4* xp = reinterpret_cast<const f32x4*>(x + (size_t)nc * FDIM + c * 8);
        xs[u][0] = xp[0];
        xs[u][1] = xp[1];
        #pragma unroll
        for (int j = 0; j < DEG; ++j) {
            int nb = sIdx[ms * DEG + j];
            g[u][j] = *reinterpret_cast<const u32x2*>(x8 + (size_t)nb * FDIM + c * 8);
        }
    }

    // combine -> bf16 LDS
    #pragma unroll
    for (int u = 0; u < 4; ++u) {
        int ms = u * 16 + slot;
        int node = base + ms;
        short8 v;
        if (node < n) {
            #pragma unroll
            for (int k = 0; k < 8; ++k) {
                unsigned sh = 8 * (k & 3);
                float s = 0.f;
                #pragma unroll
                for (int j = 0; j < DEG; ++j) {
                    unsigned w = (k < 4) ? g[u][j][0] : g[u][j][1];
                    s += fp8_to_f32((w >> sh) & 0xFFu);
                }
                float xv = (k < 4) ? xs[u][0][k & 3] : xs[u][1][k & 3];
                v[k] = f2bf(CSELF * xv + ALPHA * s);
            }
        } else {
            v = (short8)0;
        }
        *reinterpret_cast<short8*>(&sS[ms * LROW + c * 8]) = v;
    }
    __syncthreads();

    // ---- MFMA: out = relu(S @ W^T), D[(lg*4+i)][t*16+lr] mapping ----
    const int wave = tid >> 6;
    const int lane = tid & 63;
    const int lr = lane & 15;
    const int lg = lane >> 4;

    short8 afrag[4];
    const short* arow = &sS[(wave * 16 + lr) * LROW];
    #pragma unroll
    for (int kk = 0; kk < 4; ++kk)
        afrag[kk] = *reinterpret_cast<const short8*>(arow + kk * 32 + lg * 8);

    f32x4 acc[8];
    #pragma unroll
    for (int t = 0; t < 8; ++t) acc[t] = (f32x4){0.f, 0.f, 0.f, 0.f};

    #pragma unroll
    for (int t = 0; t < 8; ++t) {
        #pragma unroll
        for (int kk = 0; kk < 4; ++kk) {
            short8 bfrag = *reinterpret_cast<const short8*>(
                wswz + (((size_t)(t * 4 + kk) * 64 + lane) * 8));
            acc[t] = __builtin_amdgcn_mfma_f32_16x16x32_bf16(afrag[kk], bfrag, acc[t], 0, 0, 0);
        }
    }

    #pragma unroll
    for (int t = 0; t < 8; ++t) {
        #pragma unroll
        for (int i = 0; i < 4; ++i) {
            int nrow = base + wave * 16 + lg * 4 + i;
            if (nrow < n) {
                float v = acc[t][i];
                out[(size_t)nrow * FDIM + t * 16 + lr] = v > 0.f ? v : 0.f;
            }
        }
    }
}

// ---- fallback (fp32-gather fused, round-2 style) if d_ws too small ----
__global__ __launch_bounds__(NTHR) void shapley_fb_kernel(
    const float* __restrict__ x,
    const int* __restrict__ col,
    const short* __restrict__ wswz,
    float* __restrict__ out,
    int n)
{
    __shared__ short sS[MT * LROW];
    __shared__ int sIdx[MT * DEG];

    const int tid = threadIdx.x;
    const int base = blockIdx.x * MT;

    for (int i = tid; i < MT * DEG; i += NTHR) {
        int e = base * DEG + i;
        sIdx[i] = (e < n * DEG) ? col[e] : 0;
    }
    __syncthreads();

    for (int t = tid; t < MT * 16; t += NTHR) {
        int m = t >> 4;
        int c = t & 15;
        int node = base + m;
        float a0, a1, a2, a3, a4, a5, a6, a7;
        if (node < n) {
            const float4* xp = reinterpret_cast<const float4*>(x + (size_t)node * FDIM + c * 8);
            float4 s0 = xp[0], s1 = xp[1];
            a0 = CSELF * s0.x; a1 = CSELF * s0.y; a2 = CSELF * s0.z; a3 = CSELF * s0.w;
            a4 = CSELF * s1.x; a5 = CSELF * s1.y; a6 = CSELF * s1.z; a7 = CSELF * s1.w;
            #pragma unroll
            for (int j = 0; j < DEG; ++j) {
                int nb = sIdx[m * DEG + j];
                const float4* np = reinterpret_cast<const float4*>(x + (size_t)nb * FDIM + c * 8);
                float4 b0 = np[0], b1 = np[1];
                a0 += ALPHA * b0.x; a1 += ALPHA * b0.y; a2 += ALPHA * b0.z; a3 += ALPHA * b0.w;
                a4 += ALPHA * b1.x; a5 += ALPHA * b1.y; a6 += ALPHA * b1.z; a7 += ALPHA * b1.w;
            }
        } else {
            a0 = a1 = a2 = a3 = a4 = a5 = a6 = a7 = 0.f;
        }
        short8 v;
        v[0] = f2bf(a0); v[1] = f2bf(a1); v[2] = f2bf(a2); v[3] = f2bf(a3);
        v[4] = f2bf(a4); v[5] = f2bf(a5); v[6] = f2bf(a6); v[7] = f2bf(a7);
        *reinterpret_cast<short8*>(&sS[m * LROW + c * 8]) = v;
    }
    __syncthreads();

    const int wave = tid >> 6;
    const int lane = tid & 63;
    const int lr = lane & 15;
    const int lg = lane >> 4;

    short8 afrag[4];
    const short* arow = &sS[(wave * 16 + lr) * LROW];
    #pragma unroll
    for (int kk = 0; kk < 4; ++kk)
        afrag[kk] = *reinterpret_cast<const short8*>(arow + kk * 32 + lg * 8);

    f32x4 acc[8];
    #pragma unroll
    for (int t = 0; t < 8; ++t) acc[t] = (f32x4){0.f, 0.f, 0.f, 0.f};

    #pragma unroll
    for (int t = 0; t < 8; ++t) {
        #pragma unroll
        for (int kk = 0; kk < 4; ++kk) {
            short8 bfrag = *reinterpret_cast<const short8*>(
                wswz + (((size_t)(t * 4 + kk) * 64 + lane) * 8));
            acc[t] = __builtin_amdgcn_mfma_f32_16x16x32_bf16(afrag[kk], bfrag, acc[t], 0, 0, 0);
        }
    }

    #pragma unroll
    for (int t = 0; t < 8; ++t) {
        #pragma unroll
        for (int i = 0; i < 4; ++i) {
            int nrow = base + wave * 16 + lg * 4 + i;
            if (nrow < n) {
                float v = acc[t][i];
                out[(size_t)nrow * FDIM + t * 16 + lr] = v > 0.f ? v : 0.f;
            }
        }
    }
}

extern "C" void kernel_launch(void* const* d_in, const int* in_sizes, int n_in,
                              void* d_out, int out_size, void* d_ws, size_t ws_size,
                              hipStream_t stream) {
    const float* x  = (const float*)d_in[0];
    const int* ei   = (const int*)d_in[1];
    const float* W  = (const float*)d_in[2];
    float* out      = (float*)d_out;

    int n = in_sizes[0] / FDIM;                   // 100000 nodes
    const int* col = ei + (size_t)n * DEG;        // second row of edge_index

    short* wswz = (short*)d_ws;                   // 32 KB fragment buffer
    size_t x8_off = 32768;
    size_t need   = x8_off + (size_t)n * FDIM;    // + 12.8 MB fp8 copy of x

    hipLaunchKernelGGL(prep_w_kernel, dim3(8), dim3(256), 0, stream, W, wswz);

    int blocks = (n + MT - 1) / MT;
    if (ws_size >= need) {
        unsigned char* x8 = (unsigned char*)d_ws + x8_off;
        long total8 = (long)n * FDIM / 8;
        int cblocks = (int)((total8 + 255) / 256);
        hipLaunchKernelGGL(conv_x8_kernel, dim3(cblocks), dim3(256), 0, stream,
                           x, x8, total8);
        hipLaunchKernelGGL(shapley_gnn_kernel, dim3(blocks), dim3(NTHR), 0, stream,
                           x, x8, col, wswz, out, n);
    } else {
        hipLaunchKernelGGL(shapley_fb_kernel, dim3(blocks), dim3(NTHR), 0, stream,
                           x, col, wswz, out, n);
    }
}